// Round 6
// baseline (291.366 us; speedup 1.0000x reference)
//
#include <hip/hip_runtime.h>
#include <hip/hip_fp16.h>
#include <stdint.h>

// Problem constants (B,C_IN,L fixed by the reference)
#define BB    4
#define CIN   512
#define CRED  256
#define LL    16384
#define NBLK  256      // L / 64
#define WELEM 131072   // elements per weight matrix (256*512)

typedef _Float16 half8 __attribute__((ext_vector_type(8)));
typedef float    f32x4 __attribute__((ext_vector_type(4)));

// ---------------- LDS byte layout (74 KB -> 2 blocks/CU at 256 thr) -------
// Phase 1-2 : XT [64 pos][512 ch] fp16, rows 1024 B      0..65536
// After Bk  : Q  [64 pos][256 ch] fp16, rows 512 B       0..32768   (over XT)
//             K  [64 pos][256 ch] fp16, rows 512 B       32768..65536
// After B3  : V  [256 ch][64 pos] fp16, rows 128 B       32768..65536 (over K)
//             H  [64 pos][256 ch] fp16, rows 512 B       0..32768     (over Q)
// P  [64 i][64 j] fp16, rows 128 B                       65536..73728
// MSK 64 f32                                             73728..73984
#define XT_OFF 0
#define Q_OFF  0
#define K_OFF  32768
#define V_OFF  32768
#define H_OFF  0
#define P_OFF  65536
#define MSK_OFF 73728
#define LDS_BYTES 73984

// XOR swizzle at 16B granularity (safe for ds_read_b128); applied as
// byte_addr = linear_col ^ SWZ(row) on BOTH write and read sides.
#define SWZ(r) (((r)&7)<<4)

__global__ void convert_weights(const float* __restrict__ Wq,
                                const float* __restrict__ Wk,
                                const float* __restrict__ Wv,
                                const float* __restrict__ Wo,
                                _Float16* __restrict__ dst) {
    int i = blockIdx.x * blockDim.x + threadIdx.x;   // 0 .. 4*131072-1
    int m = i >> 17;
    int e = i & (WELEM - 1);
    const float* src = (m == 0) ? Wq : (m == 1) ? Wk : (m == 2) ? Wv : Wo;
    dst[(size_t)m * WELEM + e] = (_Float16)src[e];
}

// 256 threads (4 waves), min 2 waves/EU -> 256 unified regs/wave,
// 2 blocks/CU (74 KB LDS each) -> cross-block phase overlap.
// Register budget note: QKV accumulators (192 f32) stay in AGPRs through
// the k-loop and are scattered directly; only packed V (32 VGPR) is carried
// across softmax. Peak unified ~245 < 256 -> no spill (R5 spilled ~28 MB).
__global__ __launch_bounds__(256, 2)
void att_fused(const float* __restrict__ x1, const float* __restrict__ mask,
               const _Float16* __restrict__ W,
               const float* __restrict__ bq, const float* __restrict__ bk,
               const float* __restrict__ bv, const float* __restrict__ bo,
               float* __restrict__ out) {
    extern __shared__ char lds[];
    const int tid  = threadIdx.x;
    const int wid  = tid >> 6;         // 0..3
    const int lane = tid & 63;
    const int l15  = lane & 15;
    const int l4   = lane >> 4;
    const int blk  = blockIdx.x;
    const int b    = blk >> 8;     // batch
    const int n    = blk & 255;    // 64-pos block

    const _Float16* Wq = W;
    const _Float16* Wk = W + WELEM;
    const _Float16* Wv = W + 2 * WELEM;
    const _Float16* Wo = W + 3 * WELEM;

    // -------- Phase 1: stage X^T (pos-major, ch contiguous) + mask --------
    // Thread (jx, rg): 8 channel-rows (8rg..8rg+7 + 128i) x 4 positions.
    // Global: 16B loads, 4 rows x 256B contiguous segments per instr.
    // LDS: b128 writes, uniform bank coverage (b128 floor, no n-way scatter).
    {
        const int jx = tid & 15;          // position quad
        const int rg = tid >> 4;          // channel-octet group 0..15
        const float* xp = x1 + ((size_t)b * CIN + 8 * rg) * LL + n * 64 + 4 * jx;
        #pragma unroll
        for (int i = 0; i < 4; ++i) {
            f32x4 r[8];
            #pragma unroll
            for (int r8 = 0; r8 < 8; ++r8)
                r[r8] = *(const f32x4*)(xp + (size_t)(128 * i + r8) * LL);
            #pragma unroll
            for (int u = 0; u < 4; ++u) {
                const int j = 4 * jx + u;
                union { _Float16 h[8]; half8 v; } pk;
                #pragma unroll
                for (int r8 = 0; r8 < 8; ++r8) pk.h[r8] = (_Float16)r[r8][u];
                *(half8*)(lds + XT_OFF + j * 1024 + ((16 * rg + 256 * i) ^ SWZ(j))) = pk.v;
            }
        }
        if (tid < 64)
            *(float*)(lds + MSK_OFF + tid * 4) = mask[(size_t)b * LL + n * 64 + tid];
    }
    __syncthreads();   // B0: XT ready

    // -------- Phase 2: Q,K,V = W @ X  (M=256, K=512, N=64) ----------------
    // Wave owns 64 channels (4 passes x 16). All 192 acc regs live in AGPRs;
    // xb fragments hoisted: read once per ks for all passes.
    f32x4 aQ[4][4], aK[4][4], aV[4][4];
    #pragma unroll
    for (int p = 0; p < 4; ++p)
        #pragma unroll
        for (int q = 0; q < 4; ++q) {
            aQ[p][q] = (f32x4){0.f, 0.f, 0.f, 0.f};
            aK[p][q] = (f32x4){0.f, 0.f, 0.f, 0.f};
            aV[p][q] = (f32x4){0.f, 0.f, 0.f, 0.f};
        }
    {
        const _Float16* wq0 = Wq + (size_t)(wid * 64 + l15) * CIN + l4 * 8;
        const _Float16* wk0 = Wk + (size_t)(wid * 64 + l15) * CIN + l4 * 8;
        const _Float16* wv0 = Wv + (size_t)(wid * 64 + l15) * CIN + l4 * 8;
        #pragma unroll 4
        for (int ks = 0; ks < 16; ++ks) {
            const int kb = ks * 64 + l4 * 16;
            half8 xb[4];
            #pragma unroll
            for (int nt = 0; nt < 4; ++nt) {
                const int j = nt * 16 + l15;
                xb[nt] = *(const half8*)(lds + XT_OFF + j * 1024 + (kb ^ SWZ(j)));
            }
            #pragma unroll
            for (int pass = 0; pass < 4; ++pass) {
                const size_t wo = (size_t)pass * 16 * CIN + ks * 32;
                half8 aq = *(const half8*)(wq0 + wo);
                half8 ak = *(const half8*)(wk0 + wo);
                half8 av = *(const half8*)(wv0 + wo);
                #pragma unroll
                for (int nt = 0; nt < 4; ++nt) {
                    aQ[pass][nt] = __builtin_amdgcn_mfma_f32_16x16x32_f16(aq, xb[nt], aQ[pass][nt], 0, 0, 0);
                    aK[pass][nt] = __builtin_amdgcn_mfma_f32_16x16x32_f16(ak, xb[nt], aK[pass][nt], 0, 0, 0);
                    aV[pass][nt] = __builtin_amdgcn_mfma_f32_16x16x32_f16(av, xb[nt], aV[pass][nt], 0, 0, 0);
                }
            }
        }
    }
    __syncthreads();   // Bk: all XT reads done -> Q/K may overlay it

    // scatter Q,K directly from acc (+bias, fp16, b64); pack V to 32 VGPRs
    uint64_t vh[4][4];
    #pragma unroll
    for (int pass = 0; pass < 4; ++pass) {
        const int c0 = wid * 64 + pass * 16 + l4 * 4;
        f32x4 bqv = *(const f32x4*)(bq + c0);
        f32x4 bkv = *(const f32x4*)(bk + c0);
        f32x4 bvv = *(const f32x4*)(bv + c0);
        #pragma unroll
        for (int nt = 0; nt < 4; ++nt) {
            const int j = nt * 16 + l15;
            union { _Float16 h[4]; uint64_t q; } qp, kp, vp;
            #pragma unroll
            for (int ri = 0; ri < 4; ++ri) {
                qp.h[ri] = (_Float16)(aQ[pass][nt][ri] + bqv[ri]);
                kp.h[ri] = (_Float16)(aK[pass][nt][ri] + bkv[ri]);
                vp.h[ri] = (_Float16)(aV[pass][nt][ri] + bvv[ri]);
            }
            *(uint64_t*)(lds + Q_OFF + j * 512 + ((2 * c0) ^ SWZ(j))) = qp.q;
            *(uint64_t*)(lds + K_OFF + j * 512 + ((2 * c0) ^ SWZ(j))) = kp.q;
            vh[pass][nt] = vp.q;
        }
    }
    __syncthreads();   // Bqk: Q,K ready

    // -------- Phase 3+4: S = (Q^T K)*scale, in-register masked softmax, P --
    {
        const int i0 = wid * 16;
        f32x4 sa[4];
        #pragma unroll
        for (int jt = 0; jt < 4; ++jt) sa[jt] = (f32x4){0.f, 0.f, 0.f, 0.f};
        #pragma unroll
        for (int ks = 0; ks < 8; ++ks) {
            const int kb = ks * 64 + l4 * 16;
            const int iq = i0 + l15;
            half8 qa = *(const half8*)(lds + Q_OFF + iq * 512 + (kb ^ SWZ(iq)));
            #pragma unroll
            for (int jt = 0; jt < 4; ++jt) {
                const int jr = jt * 16 + l15;
                half8 kf = *(const half8*)(lds + K_OFF + jr * 512 + (kb ^ SWZ(jr)));
                sa[jt] = __builtin_amdgcn_mfma_f32_16x16x32_f16(qa, kf, sa[jt], 0, 0, 0);
            }
        }
        float msk[4];
        #pragma unroll
        for (int jt = 0; jt < 4; ++jt)
            msk[jt] = *(const float*)(lds + MSK_OFF + (jt * 16 + l15) * 4);
        // per-lane rows: i = i0 + l4*4 + ri ; cols: j = jt*16 + l15.
        #pragma unroll
        for (int ri = 0; ri < 4; ++ri) {
            float v[4];
            #pragma unroll
            for (int jt = 0; jt < 4; ++jt)
                v[jt] = (msk[jt] == 0.f) ? -1e30f : sa[jt][ri] * 0.0625f;
            float mx = fmaxf(fmaxf(v[0], v[1]), fmaxf(v[2], v[3]));
            mx = fmaxf(mx, __shfl_xor(mx, 1));
            mx = fmaxf(mx, __shfl_xor(mx, 2));
            mx = fmaxf(mx, __shfl_xor(mx, 4));
            mx = fmaxf(mx, __shfl_xor(mx, 8));
            float e[4], sum = 0.f;
            #pragma unroll
            for (int jt = 0; jt < 4; ++jt) { e[jt] = __expf(v[jt] - mx); sum += e[jt]; }
            sum += __shfl_xor(sum, 1);
            sum += __shfl_xor(sum, 2);
            sum += __shfl_xor(sum, 4);
            sum += __shfl_xor(sum, 8);
            const float inv = 1.f / sum;
            const int i = i0 + l4 * 4 + ri;
            #pragma unroll
            for (int jt = 0; jt < 4; ++jt) {
                const int j = jt * 16 + l15;
                *(_Float16*)(lds + P_OFF + i * 128 + ((2 * j) ^ SWZ(i))) =
                    (_Float16)(e[jt] * inv);
            }
        }
    }
    __syncthreads();   // B3: P ready; Q,K dead

    // scatter V (u16, [ch][pos]) into K's old region
    #pragma unroll
    for (int pass = 0; pass < 4; ++pass) {
        const int c0 = wid * 64 + pass * 16 + l4 * 4;
        #pragma unroll
        for (int nt = 0; nt < 4; ++nt) {
            const int j = nt * 16 + l15;
            const uint64_t v64 = vh[pass][nt];
            #pragma unroll
            for (int ri = 0; ri < 4; ++ri) {
                const int c = c0 + ri;
                *(uint16_t*)(lds + V_OFF + c * 128 + ((2 * j) ^ SWZ(c))) =
                    (uint16_t)(v64 >> (16 * ri));
            }
        }
    }
    __syncthreads();   // B4: V ready

    // -------- Phase 5: H = relu(V @ P^T)  (M=256 ch, N=64 i, K=64 j) ------
    {
        const int cb = wid * 64;
        f32x4 pv[4][4];
        #pragma unroll
        for (int m = 0; m < 4; ++m)
            #pragma unroll
            for (int q = 0; q < 4; ++q) pv[m][q] = (f32x4){0.f, 0.f, 0.f, 0.f};
        #pragma unroll
        for (int ks = 0; ks < 2; ++ks) {
            const int kb = ks * 64 + l4 * 16;
            half8 pb[4];
            #pragma unroll
            for (int nt = 0; nt < 4; ++nt) {
                const int i = nt * 16 + l15;
                pb[nt] = *(const half8*)(lds + P_OFF + i * 128 + (kb ^ SWZ(i)));
            }
            #pragma unroll
            for (int mt = 0; mt < 4; ++mt) {
                const int c = cb + mt * 16 + l15;
                half8 va = *(const half8*)(lds + V_OFF + c * 128 + (kb ^ SWZ(c)));
                #pragma unroll
                for (int nt = 0; nt < 4; ++nt)
                    pv[mt][nt] = __builtin_amdgcn_mfma_f32_16x16x32_f16(va, pb[nt], pv[mt][nt], 0, 0, 0);
            }
        }
        // relu + H [pos][ch] b64-packed into Q's old region
        #pragma unroll
        for (int mt = 0; mt < 4; ++mt) {
            const int c0 = cb + mt * 16 + l4 * 4;
            #pragma unroll
            for (int nt = 0; nt < 4; ++nt) {
                const int j = nt * 16 + l15;
                union { _Float16 h[4]; uint64_t q; } hp;
                #pragma unroll
                for (int ri = 0; ri < 4; ++ri)
                    hp.h[ri] = (_Float16)fmaxf(pv[mt][nt][ri], 0.f);
                *(uint64_t*)(lds + H_OFF + j * 512 + ((2 * c0) ^ SWZ(j))) = hp.q;
            }
        }
    }
    __syncthreads();   // B5: H ready

    // -------- Phase 6: Out = Wo @ H + bo  (M=512, K=256, N=64) ------------
    // Wave owns 128 out-channels; 2 passes x 64 keep acc at 64 regs.
    #pragma unroll
    for (int op = 0; op < 2; ++op) {
        const int mbo = wid * 128 + op * 64;
        const _Float16* wob = Wo + (size_t)(mbo + l15) * CRED + l4 * 8;
        f32x4 oa[4][4];
        #pragma unroll
        for (int m = 0; m < 4; ++m)
            #pragma unroll
            for (int q = 0; q < 4; ++q) oa[m][q] = (f32x4){0.f, 0.f, 0.f, 0.f};
        #pragma unroll 4
        for (int ks = 0; ks < 8; ++ks) {
            const int kb = ks * 64 + l4 * 16;
            half8 hb[4];
            #pragma unroll
            for (int nt = 0; nt < 4; ++nt) {
                const int i = nt * 16 + l15;
                hb[nt] = *(const half8*)(lds + H_OFF + i * 512 + (kb ^ SWZ(i)));
            }
            #pragma unroll
            for (int mt = 0; mt < 4; ++mt) {
                half8 wa = *(const half8*)(wob + mt * 16 * CRED + ks * 32);
                #pragma unroll
                for (int nt = 0; nt < 4; ++nt)
                    oa[mt][nt] = __builtin_amdgcn_mfma_f32_16x16x32_f16(wa, hb[nt], oa[mt][nt], 0, 0, 0);
            }
        }
        #pragma unroll
        for (int mt = 0; mt < 4; ++mt) {
            const int o0 = mbo + mt * 16 + l4 * 4;
            f32x4 bov = *(const f32x4*)(bo + o0);
            #pragma unroll
            for (int ri = 0; ri < 4; ++ri) {
                float* orow = out + ((size_t)b * CIN + (o0 + ri)) * LL + n * 64;
                #pragma unroll
                for (int nt = 0; nt < 4; ++nt)
                    orow[nt * 16 + l15] = oa[mt][nt][ri] + bov[ri];
            }
        }
    }
}

extern "C" void kernel_launch(void* const* d_in, const int* in_sizes, int n_in,
                              void* d_out, int out_size, void* d_ws, size_t ws_size,
                              hipStream_t stream) {
    const float* x1   = (const float*)d_in[0];
    // d_in[1] = x2 : unused by the reference
    const float* mask = (const float*)d_in[2];
    const float* Wq   = (const float*)d_in[3];
    const float* bq   = (const float*)d_in[4];
    const float* Wk   = (const float*)d_in[5];
    const float* bk   = (const float*)d_in[6];
    const float* Wv   = (const float*)d_in[7];
    const float* bv   = (const float*)d_in[8];
    const float* Wo   = (const float*)d_in[9];
    const float* bo   = (const float*)d_in[10];
    float* out = (float*)d_out;
    _Float16* wbuf = (_Float16*)d_ws;   // 1 MB of fp16 weights

    (void)hipFuncSetAttribute((const void*)att_fused,
                              hipFuncAttributeMaxDynamicSharedMemorySize, LDS_BYTES);

    convert_weights<<<2048, 256, 0, stream>>>(Wq, Wk, Wv, Wo, wbuf);
    att_fused<<<BB * NBLK, 256, LDS_BYTES, stream>>>(x1, mask, wbuf, bq, bk, bv, bo, out);
}

// Round 7
// 202.630 us; speedup vs baseline: 1.4379x; 1.4379x over previous
//
#include <hip/hip_runtime.h>
#include <hip/hip_fp16.h>
#include <stdint.h>

// Problem constants (B,C_IN,L fixed by the reference)
#define BB    4
#define CIN   512
#define CRED  256
#define LL    16384
#define NBLK  256      // L / 64
#define WELEM 131072   // elements per weight matrix (256*512)

typedef _Float16 half8 __attribute__((ext_vector_type(8)));
typedef float    f32x4 __attribute__((ext_vector_type(4)));

// XOR swizzle at 16B granularity (safe for ds_read_b128); applied as
// byte_addr = linear_col ^ SWZ(row) on BOTH write and read sides.
#define SWZ(r) (((r)&7)<<4)

// ---------------- workspace layout (elements of _Float16) -----------------
// [0, 524288)                : fp16 weights Wq,Wk,Wv,Wo (4 x 131072)
// Q: 524288 + t*16384        : per-tile [64 pos][256 ch]
// K: +16777216               : per-tile [64 pos][256 ch]
// V: +33554432               : per-tile [256 ch][64 pos]
#define QBASE   524288
#define TILE_E  16384
#define MAT_E   16777216   // 1024 tiles * 16384
#define WS_NEED ((size_t)(QBASE + 3 * MAT_E) * 2)   // 101,711,872 bytes

__global__ void convert_weights(const float* __restrict__ Wq,
                                const float* __restrict__ Wk,
                                const float* __restrict__ Wv,
                                const float* __restrict__ Wo,
                                _Float16* __restrict__ dst) {
    int i = blockIdx.x * blockDim.x + threadIdx.x;   // 0 .. 4*131072-1
    int m = i >> 17;
    int e = i & (WELEM - 1);
    const float* src = (m == 0) ? Wq : (m == 1) ? Wk : (m == 2) ? Wv : Wo;
    dst[(size_t)m * WELEM + e] = (_Float16)src[e];
}

// ======================= Kernel A: QKV = W @ X =============================
// Per (b,n) block: stage XT once (one barrier), then 3 passes (Q,K,V) of a
// [64ch x 512k x 64pos] GEMM per wave, storing straight from acc to ws.
// Live regs per pass: 64 acc + ~40 working -> no spill at 2 blocks/CU.
__global__ __launch_bounds__(256, 2)
void qkv_gemm(const float* __restrict__ x1, const _Float16* __restrict__ W,
              const float* __restrict__ bq, const float* __restrict__ bk,
              const float* __restrict__ bv, _Float16* __restrict__ ws) {
    extern __shared__ char lds[];          // XT [64 pos][512 ch] fp16, rows 1024 B
    const int tid = threadIdx.x;
    const int wid = tid >> 6;
    const int l15 = tid & 15;              // lane&15 (wave-uniform per group)
    const int l4  = (tid & 63) >> 4;
    const int b   = blockIdx.x >> 8;
    const int n   = blockIdx.x & 255;

    // -------- stage X^T: b128 LDS writes (conflict-free, verified R6) -----
    {
        const int jx = tid & 15;           // position quad
        const int rg = tid >> 4;           // channel-octet group 0..15
        const float* xp = x1 + ((size_t)b * CIN + 8 * rg) * LL + n * 64 + 4 * jx;
        #pragma unroll
        for (int i = 0; i < 4; ++i) {
            f32x4 r[8];
            #pragma unroll
            for (int r8 = 0; r8 < 8; ++r8)
                r[r8] = *(const f32x4*)(xp + (size_t)(128 * i + r8) * LL);
            #pragma unroll
            for (int u = 0; u < 4; ++u) {
                const int j = 4 * jx + u;
                union { _Float16 h[8]; half8 v; } pk;
                #pragma unroll
                for (int r8 = 0; r8 < 8; ++r8) pk.h[r8] = (_Float16)r[r8][u];
                *(half8*)(lds + j * 1024 + ((16 * rg + 256 * i) ^ SWZ(j))) = pk.v;
            }
        }
    }
    __syncthreads();   // only barrier in this kernel

    const size_t t = (size_t)blockIdx.x * TILE_E;
    #pragma unroll
    for (int p = 0; p < 3; ++p) {
        f32x4 am[4][4];
        #pragma unroll
        for (int m = 0; m < 4; ++m)
            #pragma unroll
            for (int q = 0; q < 4; ++q) am[m][q] = (f32x4){0.f, 0.f, 0.f, 0.f};
        const _Float16* wp = W + (size_t)p * WELEM + (size_t)(wid * 64 + l15) * CIN + l4 * 8;
        #pragma unroll 4
        for (int ks = 0; ks < 16; ++ks) {
            const int kb = ks * 64 + l4 * 16;
            half8 xb[4];
            #pragma unroll
            for (int nt = 0; nt < 4; ++nt) {
                const int j = nt * 16 + l15;
                xb[nt] = *(const half8*)(lds + j * 1024 + (kb ^ SWZ(j)));
            }
            #pragma unroll
            for (int mt = 0; mt < 4; ++mt) {
                half8 wf = *(const half8*)(wp + mt * 16 * CIN + ks * 32);
                #pragma unroll
                for (int nt = 0; nt < 4; ++nt)
                    am[mt][nt] = __builtin_amdgcn_mfma_f32_16x16x32_f16(wf, xb[nt], am[mt][nt], 0, 0, 0);
            }
        }
        const float* bias = (p == 0) ? bq : (p == 1) ? bk : bv;
        if (p < 2) {
            _Float16* dst = ws + QBASE + (size_t)p * MAT_E + t;   // [pos][ch]
            #pragma unroll
            for (int mt = 0; mt < 4; ++mt) {
                const int c0 = wid * 64 + mt * 16 + l4 * 4;
                f32x4 b4 = *(const f32x4*)(bias + c0);
                #pragma unroll
                for (int nt = 0; nt < 4; ++nt) {
                    const int j = nt * 16 + l15;
                    union { _Float16 h[4]; uint64_t q; } pk;
                    #pragma unroll
                    for (int ri = 0; ri < 4; ++ri)
                        pk.h[ri] = (_Float16)(am[mt][nt][ri] + b4[ri]);
                    *(uint64_t*)(dst + (size_t)j * 256 + c0) = pk.q;
                }
            }
        } else {
            _Float16* dst = ws + QBASE + 2 * (size_t)MAT_E + t;   // [ch][pos]
            #pragma unroll
            for (int mt = 0; mt < 4; ++mt) {
                const int c0 = wid * 64 + mt * 16 + l4 * 4;
                f32x4 b4 = *(const f32x4*)(bias + c0);
                #pragma unroll
                for (int nt = 0; nt < 4; ++nt) {
                    const int j = nt * 16 + l15;
                    #pragma unroll
                    for (int ri = 0; ri < 4; ++ri)
                        dst[(size_t)(c0 + ri) * 64 + j] = (_Float16)(am[mt][nt][ri] + b4[ri]);
                }
            }
        }
    }
}

// ================ Kernel B: attention + output projection ==================
// Q,K,V fragments read DIRECT from global (L2/L3-resident ws tiles) -> no
// staging barrier. LDS only for P (8 KB) and H (32 KB): 41 KB -> 3 blocks/CU.
#define BH_OFF 0
#define BP_OFF 32768
#define LDS_B  40960

__global__ __launch_bounds__(256, 3)
void attn_out(const float* __restrict__ mask, const _Float16* __restrict__ ws,
              const float* __restrict__ bo, float* __restrict__ out) {
    extern __shared__ char lds[];
    const int tid = threadIdx.x;
    const int wid = tid >> 6;
    const int l15 = tid & 15;
    const int l4  = (tid & 63) >> 4;
    const int b   = blockIdx.x >> 8;
    const int n   = blockIdx.x & 255;

    const size_t t = (size_t)blockIdx.x * TILE_E;
    const _Float16* qt = ws + QBASE + t;
    const _Float16* kt = qt + MAT_E;
    const _Float16* vt = qt + 2 * (size_t)MAT_E;
    const _Float16* Wo = ws + 3 * (size_t)WELEM;

    // -------- S = (Q^T K)*scale + in-register masked softmax -> P ---------
    {
        const int i0 = wid * 16;
        f32x4 sa[4];
        #pragma unroll
        for (int jt = 0; jt < 4; ++jt) sa[jt] = (f32x4){0.f, 0.f, 0.f, 0.f};
        #pragma unroll
        for (int ks = 0; ks < 8; ++ks) {
            half8 qa = *(const half8*)(qt + (size_t)(i0 + l15) * 256 + ks * 32 + l4 * 8);
            #pragma unroll
            for (int jt = 0; jt < 4; ++jt) {
                half8 kf = *(const half8*)(kt + (size_t)(jt * 16 + l15) * 256 + ks * 32 + l4 * 8);
                sa[jt] = __builtin_amdgcn_mfma_f32_16x16x32_f16(qa, kf, sa[jt], 0, 0, 0);
            }
        }
        float msk[4];
        #pragma unroll
        for (int jt = 0; jt < 4; ++jt)
            msk[jt] = mask[(size_t)b * LL + n * 64 + jt * 16 + l15];
        // per-lane rows: i = i0 + l4*4 + ri ; cols: j = jt*16 + l15.
        #pragma unroll
        for (int ri = 0; ri < 4; ++ri) {
            float v[4];
            #pragma unroll
            for (int jt = 0; jt < 4; ++jt)
                v[jt] = (msk[jt] == 0.f) ? -1e30f : sa[jt][ri] * 0.0625f;
            float mx = fmaxf(fmaxf(v[0], v[1]), fmaxf(v[2], v[3]));
            mx = fmaxf(mx, __shfl_xor(mx, 1));
            mx = fmaxf(mx, __shfl_xor(mx, 2));
            mx = fmaxf(mx, __shfl_xor(mx, 4));
            mx = fmaxf(mx, __shfl_xor(mx, 8));
            float e[4], sum = 0.f;
            #pragma unroll
            for (int jt = 0; jt < 4; ++jt) { e[jt] = __expf(v[jt] - mx); sum += e[jt]; }
            sum += __shfl_xor(sum, 1);
            sum += __shfl_xor(sum, 2);
            sum += __shfl_xor(sum, 4);
            sum += __shfl_xor(sum, 8);
            const float inv = 1.f / sum;
            const int i = i0 + l4 * 4 + ri;
            #pragma unroll
            for (int jt = 0; jt < 4; ++jt) {
                const int j = jt * 16 + l15;
                *(_Float16*)(lds + BP_OFF + i * 128 + ((2 * j) ^ SWZ(i))) =
                    (_Float16)(e[jt] * inv);
            }
        }
    }
    __syncthreads();   // P ready

    // -------- H = relu(V @ P^T)  (V frags direct from global) -------------
    {
        const int cb = wid * 64;
        f32x4 pv[4][4];
        #pragma unroll
        for (int m = 0; m < 4; ++m)
            #pragma unroll
            for (int q = 0; q < 4; ++q) pv[m][q] = (f32x4){0.f, 0.f, 0.f, 0.f};
        #pragma unroll
        for (int ks = 0; ks < 2; ++ks) {
            const int kb = ks * 64 + l4 * 16;
            half8 pb[4];
            #pragma unroll
            for (int nt = 0; nt < 4; ++nt) {
                const int i = nt * 16 + l15;
                pb[nt] = *(const half8*)(lds + BP_OFF + i * 128 + (kb ^ SWZ(i)));
            }
            #pragma unroll
            for (int mt = 0; mt < 4; ++mt) {
                half8 va = *(const half8*)(vt + (size_t)(cb + mt * 16 + l15) * 64 + ks * 32 + l4 * 8);
                #pragma unroll
                for (int nt = 0; nt < 4; ++nt)
                    pv[mt][nt] = __builtin_amdgcn_mfma_f32_16x16x32_f16(va, pb[nt], pv[mt][nt], 0, 0, 0);
            }
        }
        // relu + H [pos][ch] b64-packed
        #pragma unroll
        for (int mt = 0; mt < 4; ++mt) {
            const int c0 = cb + mt * 16 + l4 * 4;
            #pragma unroll
            for (int nt = 0; nt < 4; ++nt) {
                const int j = nt * 16 + l15;
                union { _Float16 h[4]; uint64_t q; } hp;
                #pragma unroll
                for (int ri = 0; ri < 4; ++ri)
                    hp.h[ri] = (_Float16)fmaxf(pv[mt][nt][ri], 0.f);
                *(uint64_t*)(lds + BH_OFF + j * 512 + ((2 * c0) ^ SWZ(j))) = hp.q;
            }
        }
    }
    __syncthreads();   // H ready

    // -------- Out = Wo @ H + bo  (M=512, K=256, N=64) ---------------------
    #pragma unroll
    for (int op = 0; op < 2; ++op) {
        const int mbo = wid * 128 + op * 64;
        const _Float16* wob = Wo + (size_t)(mbo + l15) * CRED + l4 * 8;
        f32x4 oa[4][4];
        #pragma unroll
        for (int m = 0; m < 4; ++m)
            #pragma unroll
            for (int q = 0; q < 4; ++q) oa[m][q] = (f32x4){0.f, 0.f, 0.f, 0.f};
        #pragma unroll 4
        for (int ks = 0; ks < 8; ++ks) {
            const int kb = ks * 64 + l4 * 16;
            half8 hb[4];
            #pragma unroll
            for (int nt = 0; nt < 4; ++nt) {
                const int i = nt * 16 + l15;
                hb[nt] = *(const half8*)(lds + BH_OFF + i * 512 + (kb ^ SWZ(i)));
            }
            #pragma unroll
            for (int mt = 0; mt < 4; ++mt) {
                half8 wa = *(const half8*)(wob + mt * 16 * CRED + ks * 32);
                #pragma unroll
                for (int nt = 0; nt < 4; ++nt)
                    oa[mt][nt] = __builtin_amdgcn_mfma_f32_16x16x32_f16(wa, hb[nt], oa[mt][nt], 0, 0, 0);
            }
        }
        #pragma unroll
        for (int mt = 0; mt < 4; ++mt) {
            const int o0 = mbo + mt * 16 + l4 * 4;
            f32x4 bov = *(const f32x4*)(bo + o0);
            #pragma unroll
            for (int ri = 0; ri < 4; ++ri) {
                float* orow = out + ((size_t)b * CIN + (o0 + ri)) * LL + n * 64;
                #pragma unroll
                for (int nt = 0; nt < 4; ++nt)
                    orow[nt * 16 + l15] = oa[mt][nt][ri] + bov[ri];
            }
        }
    }
}

// ================= Fallback: R5 fused kernel (verified, 168 us) ============
#define XT_OFF 0
#define Q_OFF  0
#define K_OFF  32768
#define V_OFF  32768
#define H_OFF  0
#define P_OFF  65536
#define MSK_OFF 73728
#define LDS_BYTES 73984

__global__ __launch_bounds__(256, 2)
void att_fused(const float* __restrict__ x1, const float* __restrict__ mask,
               const _Float16* __restrict__ W,
               const float* __restrict__ bq, const float* __restrict__ bk,
               const float* __restrict__ bv, const float* __restrict__ bo,
               float* __restrict__ out) {
    extern __shared__ char lds[];
    const int tid  = threadIdx.x;
    const int wid  = tid >> 6;
    const int lane = tid & 63;
    const int l15  = lane & 15;
    const int l4   = lane >> 4;
    const int blk  = blockIdx.x;
    const int b    = blk >> 8;
    const int n    = blk & 255;

    const _Float16* Wq = W;
    const _Float16* Wk = W + WELEM;
    const _Float16* Wv = W + 2 * WELEM;
    const _Float16* Wo = W + 3 * WELEM;

    {
        const int jx = tid & 15;
        const int rb = tid >> 4;
        const float* xbase = x1 + ((size_t)b * CIN + 2 * rb) * LL + n * 64 + 4 * jx;
        #pragma unroll
        for (int i = 0; i < 16; ++i) {
            f32x4 a = *(const f32x4*)(xbase + (size_t)(32 * i) * LL);
            f32x4 c = *(const f32x4*)(xbase + (size_t)(32 * i + 1) * LL);
            const int col = 4 * rb + 64 * i;
            #pragma unroll
            for (int u = 0; u < 4; ++u) {
                union { _Float16 h[2]; uint32_t w; } p;
                p.h[0] = (_Float16)a[u];
                p.h[1] = (_Float16)c[u];
                const int j = 4 * jx + u;
                *(uint32_t*)(lds + XT_OFF + j * 1024 + (col ^ SWZ(j))) = p.w;
            }
        }
        if (tid < 64)
            *(float*)(lds + MSK_OFF + tid * 4) = mask[(size_t)b * LL + n * 64 + tid];
    }
    __syncthreads();

    uint64_t qh[4][4], kh[4][4], vh[4][4];
    #pragma unroll
    for (int pass = 0; pass < 4; ++pass) {
        f32x4 aQ[4], aK[4], aV[4];
        #pragma unroll
        for (int q = 0; q < 4; ++q) {
            aQ[q] = (f32x4){0.f, 0.f, 0.f, 0.f};
            aK[q] = (f32x4){0.f, 0.f, 0.f, 0.f};
            aV[q] = (f32x4){0.f, 0.f, 0.f, 0.f};
        }
        const int mrow = wid * 64 + pass * 16 + l15;
        const _Float16* wqp = Wq + (size_t)mrow * CIN + l4 * 8;
        const _Float16* wkp = Wk + (size_t)mrow * CIN + l4 * 8;
        const _Float16* wvp = Wv + (size_t)mrow * CIN + l4 * 8;
        #pragma unroll 4
        for (int ks = 0; ks < 16; ++ks) {
            const int kb = ks * 64 + l4 * 16;
            half8 xb[4];
            #pragma unroll
            for (int nt = 0; nt < 4; ++nt) {
                const int j = nt * 16 + l15;
                xb[nt] = *(const half8*)(lds + XT_OFF + j * 1024 + (kb ^ SWZ(j)));
            }
            half8 aq = *(const half8*)(wqp + ks * 32);
            half8 ak = *(const half8*)(wkp + ks * 32);
            half8 av = *(const half8*)(wvp + ks * 32);
            #pragma unroll
            for (int nt = 0; nt < 4; ++nt) {
                aQ[nt] = __builtin_amdgcn_mfma_f32_16x16x32_f16(aq, xb[nt], aQ[nt], 0, 0, 0);
                aK[nt] = __builtin_amdgcn_mfma_f32_16x16x32_f16(ak, xb[nt], aK[nt], 0, 0, 0);
                aV[nt] = __builtin_amdgcn_mfma_f32_16x16x32_f16(av, xb[nt], aV[nt], 0, 0, 0);
            }
        }
        const int c0 = wid * 64 + pass * 16 + l4 * 4;
        f32x4 bqv = *(const f32x4*)(bq + c0);
        f32x4 bkv = *(const f32x4*)(bk + c0);
        f32x4 bvv = *(const f32x4*)(bv + c0);
        #pragma unroll
        for (int nt = 0; nt < 4; ++nt) {
            union { _Float16 h[4]; uint64_t q; } qp, kp, vp;
            #pragma unroll
            for (int ri = 0; ri < 4; ++ri) {
                qp.h[ri] = (_Float16)(aQ[nt][ri] + bqv[ri]);
                kp.h[ri] = (_Float16)(aK[nt][ri] + bkv[ri]);
                vp.h[ri] = (_Float16)(aV[nt][ri] + bvv[ri]);
            }
            qh[pass][nt] = qp.q;
            kh[pass][nt] = kp.q;
            vh[pass][nt] = vp.q;
        }
    }
    __syncthreads();

    #pragma unroll
    for (int pass = 0; pass < 4; ++pass) {
        const int c0 = wid * 64 + pass * 16 + l4 * 4;
        #pragma unroll
        for (int nt = 0; nt < 4; ++nt) {
            const int j = nt * 16 + l15;
            *(uint64_t*)(lds + Q_OFF + j * 512 + ((2 * c0) ^ SWZ(j))) = qh[pass][nt];
            *(uint64_t*)(lds + K_OFF + j * 512 + ((2 * c0) ^ SWZ(j))) = kh[pass][nt];
        }
    }
    __syncthreads();

    {
        const int i0 = wid * 16;
        f32x4 sa[4];
        #pragma unroll
        for (int jt = 0; jt < 4; ++jt) sa[jt] = (f32x4){0.f, 0.f, 0.f, 0.f};
        #pragma unroll
        for (int ks = 0; ks < 8; ++ks) {
            const int kb = ks * 64 + l4 * 16;
            const int iq = i0 + l15;
            half8 qa = *(const half8*)(lds + Q_OFF + iq * 512 + (kb ^ SWZ(iq)));
            #pragma unroll
            for (int jt = 0; jt < 4; ++jt) {
                const int jr = jt * 16 + l15;
                half8 kf = *(const half8*)(lds + K_OFF + jr * 512 + (kb ^ SWZ(jr)));
                sa[jt] = __builtin_amdgcn_mfma_f32_16x16x32_f16(qa, kf, sa[jt], 0, 0, 0);
            }
        }
        float msk[4];
        #pragma unroll
        for (int jt = 0; jt < 4; ++jt)
            msk[jt] = *(const float*)(lds + MSK_OFF + (jt * 16 + l15) * 4);
        #pragma unroll
        for (int ri = 0; ri < 4; ++ri) {
            float v[4];
            #pragma unroll
            for (int jt = 0; jt < 4; ++jt)
                v[jt] = (msk[jt] == 0.f) ? -1e30f : sa[jt][ri] * 0.0625f;
            float mx = fmaxf(fmaxf(v[0], v[1]), fmaxf(v[2], v[3]));
            mx = fmaxf(mx, __shfl_xor(mx, 1));
            mx = fmaxf(mx, __shfl_xor(mx, 2));
            mx = fmaxf(mx, __shfl_xor(mx, 4));
            mx = fmaxf(mx, __shfl_xor(mx, 8));
            float e[4], sum = 0.f;
            #pragma unroll
            for (int jt = 0; jt < 4; ++jt) { e[jt] = __expf(v[jt] - mx); sum += e[jt]; }
            sum += __shfl_xor(sum, 1);
            sum += __shfl_xor(sum, 2);
            sum += __shfl_xor(sum, 4);
            sum += __shfl_xor(sum, 8);
            const float inv = 1.f / sum;
            const int i = i0 + l4 * 4 + ri;
            #pragma unroll
            for (int jt = 0; jt < 4; ++jt) {
                const int j = jt * 16 + l15;
                *(_Float16*)(lds + P_OFF + i * 128 + ((2 * j) ^ SWZ(i))) =
                    (_Float16)(e[jt] * inv);
            }
        }
    }
    __syncthreads();

    #pragma unroll
    for (int pass = 0; pass < 4; ++pass) {
        const int c0 = wid * 64 + pass * 16 + l4 * 4;
        #pragma unroll
        for (int nt = 0; nt < 4; ++nt) {
            const int j = nt * 16 + l15;
            const uint64_t v64 = vh[pass][nt];
            #pragma unroll
            for (int ri = 0; ri < 4; ++ri) {
                const int c = c0 + ri;
                *(uint16_t*)(lds + V_OFF + c * 128 + ((2 * j) ^ SWZ(c))) =
                    (uint16_t)(v64 >> (16 * ri));
            }
        }
    }
    __syncthreads();

    {
        const int cb = wid * 64;
        f32x4 pv[4][4];
        #pragma unroll
        for (int m = 0; m < 4; ++m)
            #pragma unroll
            for (int q = 0; q < 4; ++q) pv[m][q] = (f32x4){0.f, 0.f, 0.f, 0.f};
        #pragma unroll
        for (int ks = 0; ks < 2; ++ks) {
            const int kb = ks * 64 + l4 * 16;
            half8 pb[4];
            #pragma unroll
            for (int nt = 0; nt < 4; ++nt) {
                const int i = nt * 16 + l15;
                pb[nt] = *(const half8*)(lds + P_OFF + i * 128 + (kb ^ SWZ(i)));
            }
            #pragma unroll
            for (int mt = 0; mt < 4; ++mt) {
                const int c = cb + mt * 16 + l15;
                half8 va = *(const half8*)(lds + V_OFF + c * 128 + ((kb) ^ SWZ(c)));
                #pragma unroll
                for (int nt = 0; nt < 4; ++nt)
                    pv[mt][nt] = __builtin_amdgcn_mfma_f32_16x16x32_f16(va, pb[nt], pv[mt][nt], 0, 0, 0);
            }
        }
        #pragma unroll
        for (int mt = 0; mt < 4; ++mt) {
            const int c0 = cb + mt * 16 + l4 * 4;
            #pragma unroll
            for (int nt = 0; nt < 4; ++nt) {
                const int j = nt * 16 + l15;
                union { _Float16 h[4]; uint64_t q; } hp;
                #pragma unroll
                for (int ri = 0; ri < 4; ++ri)
                    hp.h[ri] = (_Float16)fmaxf(pv[mt][nt][ri], 0.f);
                *(uint64_t*)(lds + H_OFF + j * 512 + ((2 * c0) ^ SWZ(j))) = hp.q;
            }
        }
    }
    __syncthreads();

    #pragma unroll
    for (int op = 0; op < 2; ++op) {
        const int mbo = wid * 128 + op * 64;
        const _Float16* wob = Wo + (size_t)(mbo + l15) * CRED + l4 * 8;
        f32x4 oa[4][4];
        #pragma unroll
        for (int m = 0; m < 4; ++m)
            #pragma unroll
            for (int q = 0; q < 4; ++q) oa[m][q] = (f32x4){0.f, 0.f, 0.f, 0.f};
        #pragma unroll 4
        for (int ks = 0; ks < 8; ++ks) {
            const int kb = ks * 64 + l4 * 16;
            half8 hb[4];
            #pragma unroll
            for (int nt = 0; nt < 4; ++nt) {
                const int i = nt * 16 + l15;
                hb[nt] = *(const half8*)(lds + H_OFF + i * 512 + (kb ^ SWZ(i)));
            }
            #pragma unroll
            for (int mt = 0; mt < 4; ++mt) {
                half8 wa = *(const half8*)(wob + mt * 16 * CRED + ks * 32);
                #pragma unroll
                for (int nt = 0; nt < 4; ++nt)
                    oa[mt][nt] = __builtin_amdgcn_mfma_f32_16x16x32_f16(wa, hb[nt], oa[mt][nt], 0, 0, 0);
            }
        }
        #pragma unroll
        for (int mt = 0; mt < 4; ++mt) {
            const int o0 = mbo + mt * 16 + l4 * 4;
            f32x4 bov = *(const f32x4*)(bo + o0);
            #pragma unroll
            for (int ri = 0; ri < 4; ++ri) {
                float* orow = out + ((size_t)b * CIN + (o0 + ri)) * LL + n * 64;
                #pragma unroll
                for (int nt = 0; nt < 4; ++nt)
                    orow[nt * 16 + l15] = oa[mt][nt][ri] + bov[ri];
            }
        }
    }
}

extern "C" void kernel_launch(void* const* d_in, const int* in_sizes, int n_in,
                              void* d_out, int out_size, void* d_ws, size_t ws_size,
                              hipStream_t stream) {
    const float* x1   = (const float*)d_in[0];
    // d_in[1] = x2 : unused by the reference
    const float* mask = (const float*)d_in[2];
    const float* Wq   = (const float*)d_in[3];
    const float* bq   = (const float*)d_in[4];
    const float* Wk   = (const float*)d_in[5];
    const float* bk   = (const float*)d_in[6];
    const float* Wv   = (const float*)d_in[7];
    const float* bv   = (const float*)d_in[8];
    const float* Wo   = (const float*)d_in[9];
    const float* bo   = (const float*)d_in[10];
    float* out = (float*)d_out;
    _Float16* wbuf = (_Float16*)d_ws;

    convert_weights<<<2048, 256, 0, stream>>>(Wq, Wk, Wv, Wo, wbuf);

    if (ws_size >= WS_NEED) {
        (void)hipFuncSetAttribute((const void*)qkv_gemm,
                                  hipFuncAttributeMaxDynamicSharedMemorySize, 65536);
        qkv_gemm<<<BB * NBLK, 256, 65536, stream>>>(x1, wbuf, bq, bk, bv, wbuf);
        attn_out<<<BB * NBLK, 256, LDS_B, stream>>>(mask, wbuf, bo, out);
    } else {
        (void)hipFuncSetAttribute((const void*)att_fused,
                                  hipFuncAttributeMaxDynamicSharedMemorySize, LDS_BYTES);
        att_fused<<<BB * NBLK, 256, LDS_BYTES, stream>>>(x1, mask, wbuf, bq, bk, bv, bo, out);
    }
}

// Round 8
// 187.126 us; speedup vs baseline: 1.5571x; 1.0829x over previous
//
#include <hip/hip_runtime.h>
#include <hip/hip_fp16.h>
#include <stdint.h>

// Problem constants (B,C_IN,L fixed by the reference)
#define BB    4
#define CIN   512
#define CRED  256
#define LL    16384
#define NBLK  256      // L / 64
#define WELEM 131072   // elements per weight matrix (256*512)

typedef _Float16 half8 __attribute__((ext_vector_type(8)));
typedef float    f32x4 __attribute__((ext_vector_type(4)));

#define SWZ(r) (((r)&7)<<4)

// ---------------- workspace layout (elements of _Float16) -----------------
// [0, 524288)              : fp16 weights Wq,Wk,Wv,Wo (4 x 131072)
// Q: QBASE                 : [b][pos 16384][ch 256]
// K: QBASE +   MAT_E       : [b][pos 16384][ch 256]
// V: QBASE + 2*MAT_E       : [b][ch 256][pos 16384]
#define QBASE   524288
#define MAT_E   16777216   // 4 * 16384 * 256
#define WS_NEED ((size_t)(QBASE + 3 * MAT_E) * 2)   // ~101 MB

__global__ void convert_weights(const float* __restrict__ Wq,
                                const float* __restrict__ Wk,
                                const float* __restrict__ Wv,
                                const float* __restrict__ Wo,
                                _Float16* __restrict__ dst) {
    int i = blockIdx.x * blockDim.x + threadIdx.x;
    int m = i >> 17;
    int e = i & (WELEM - 1);
    const float* src = (m == 0) ? Wq : (m == 1) ? Wk : (m == 2) ? Wv : Wo;
    dst[(size_t)m * WELEM + e] = (_Float16)src[e];
}

// ======================= Kernel A: QKV = W @ X  (v2) =======================
// BN=128 pos/block, BK=64 double-buffered X chunks, 3 passes (Q,K,V).
// LDS: dbuf 2x16KB @0, repack 32KB @32768  -> 64KB -> 2 blocks/CU.
// acc 32 f32x4 (AGPR) + 8 f32x4 staging (VGPR): ~230 unified, no spill.
__global__ __launch_bounds__(256, 2)
void qkv_gemm(const float* __restrict__ x1, const _Float16* __restrict__ W,
              const float* __restrict__ bq, const float* __restrict__ bk,
              const float* __restrict__ bv, _Float16* __restrict__ ws) {
    extern __shared__ char lds[];
    const int tid = threadIdx.x;
    const int wid = tid >> 6;
    const int l15 = tid & 15;
    const int l4  = (tid & 63) >> 4;
    const int b   = blockIdx.x >> 7;        // 512 blocks: 4 batches x 128 groups
    const int g   = blockIdx.x & 127;
    const int pos0 = g * 128;

    const int jx = tid & 31;                // pos quad 0..31
    const int rg = tid >> 5;                // ch octet 0..7

    const float* xb0 = x1 + (size_t)b * CIN * LL + pos0 + 4 * jx;

    f32x4 st[8];   // in-flight X chunk (issue-early / commit-late)

    // ---- issue global loads for chunk kc (2x512B segments per instr) ----
    #define X_ISSUE(KC) do {                                                  \
        const float* xp_ = xb0 + (size_t)((KC) * 64 + 8 * rg) * LL;           \
        _Pragma("unroll")                                                     \
        for (int r8_ = 0; r8_ < 8; ++r8_)                                     \
            st[r8_] = *(const f32x4*)(xp_ + (size_t)r8_ * LL);                \
    } while (0)

    // ---- convert+transpose-commit into buffer half CUR ([n][64k] fp16) ---
    #define X_COMMIT(CUR) do {                                                \
        char* bp_ = lds + (CUR) * 16384;                                      \
        _Pragma("unroll")                                                     \
        for (int u_ = 0; u_ < 4; ++u_) {                                      \
            const int n_ = 4 * jx + u_;                                       \
            union { _Float16 h[8]; half8 v; } pk_;                            \
            _Pragma("unroll")                                                 \
            for (int r8_ = 0; r8_ < 8; ++r8_)                                 \
                pk_.h[r8_] = (_Float16)st[r8_][u_];                           \
            *(half8*)(bp_ + n_ * 128 + ((16 * rg) ^ SWZ(n_))) = pk_.v;        \
        }                                                                     \
    } while (0)

    // prologue: chunk 0
    X_ISSUE(0);
    X_COMMIT(0);
    __syncthreads();
    int cur = 0;

    #pragma unroll
    for (int p = 0; p < 3; ++p) {
        f32x4 acc[4][8];
        #pragma unroll
        for (int mt = 0; mt < 4; ++mt)
            #pragma unroll
            for (int nt = 0; nt < 8; ++nt) acc[mt][nt] = (f32x4){0.f, 0.f, 0.f, 0.f};

        for (int kc = 0; kc < 8; ++kc) {
            const bool hn = !(p == 2 && kc == 7);
            if (hn) X_ISSUE((kc + 1) & 7);     // next chunk (wraps to 0 for next pass)

            // ---- compute chunk kc from LDS buf[cur] ----
            const _Float16* wp = W + (size_t)p * WELEM
                               + (size_t)(wid * 64 + l15) * CIN + kc * 64 + l4 * 8;
            char* bp = lds + cur * 16384;
            #pragma unroll
            for (int ks = 0; ks < 2; ++ks) {
                half8 xf[8];
                #pragma unroll
                for (int nt = 0; nt < 8; ++nt) {
                    const int n = nt * 16 + l15;
                    xf[nt] = *(const half8*)(bp + n * 128 + ((ks * 64 + l4 * 16) ^ SWZ(n)));
                }
                #pragma unroll
                for (int mt = 0; mt < 4; ++mt) {
                    half8 wf = *(const half8*)(wp + mt * 16 * CIN + ks * 32);
                    #pragma unroll
                    for (int nt = 0; nt < 8; ++nt)
                        acc[mt][nt] = __builtin_amdgcn_mfma_f32_16x16x32_f16(wf, xf[nt], acc[mt][nt], 0, 0, 0);
                }
            }
            __syncthreads();                   // all reads of buf[cur] done
            if (hn) X_COMMIT(cur ^ 1);         // write next chunk (loads now landed)
            cur ^= 1;
            __syncthreads();                   // next chunk visible
        }

        // ---- store pass results: LDS repack -> coalesced b128 stores ----
        char* rp = lds + 32768;
        if (p < 2) {
            // Q/K: ws [b][pos][ch]; repack [64n][256ch] per round (2 rounds)
            _Float16* qdst = ws + QBASE + (size_t)p * MAT_E
                           + ((size_t)b * LL + pos0) * CRED;
            const float* bias = p ? bk : bq;
            #pragma unroll
            for (int r = 0; r < 2; ++r) {
                #pragma unroll
                for (int mt = 0; mt < 4; ++mt) {
                    const int c0 = wid * 64 + mt * 16 + l4 * 4;
                    f32x4 bb = *(const f32x4*)(bias + c0);
                    #pragma unroll
                    for (int q4 = 0; q4 < 4; ++q4) {
                        const int nt = 4 * r + q4;
                        const int nn = (nt * 16 + l15) - 64 * r;   // 0..63
                        union { _Float16 h[4]; uint64_t q; } pk;
                        #pragma unroll
                        for (int ri = 0; ri < 4; ++ri)
                            pk.h[ri] = (_Float16)(acc[mt][nt][ri] + bb[ri]);
                        *(uint64_t*)(rp + nn * 512 + ((2 * c0) ^ SWZ(nn))) = pk.q;
                    }
                }
                __syncthreads();
                #pragma unroll
                for (int i = 0; i < 8; ++i) {
                    const int chunk = i * 4096 + tid * 16;
                    const int nn = chunk >> 9;
                    const int mc = chunk & 511;
                    half8 v = *(const half8*)(rp + nn * 512 + (mc ^ SWZ(nn)));
                    *(half8*)((char*)qdst + (size_t)(64 * r + nn) * 512 + mc) = v;
                }
                __syncthreads();
            }
        } else {
            // V: ws [b][ch][pos]; repack [128ch][128pos] per round (2 rounds)
            _Float16* vdst = ws + QBASE + 2 * (size_t)MAT_E
                           + (size_t)b * CRED * LL + pos0;
            #pragma unroll
            for (int r = 0; r < 2; ++r) {
                if ((wid >> 1) == r) {
                    const int mw = (wid & 1) * 64;
                    #pragma unroll
                    for (int mt = 0; mt < 4; ++mt) {
                        const int c0 = wid * 64 + mt * 16 + l4 * 4;
                        f32x4 bb = *(const f32x4*)(bv + c0);
                        #pragma unroll
                        for (int nt = 0; nt < 8; ++nt) {
                            const int n = nt * 16 + l15;
                            #pragma unroll
                            for (int ri = 0; ri < 4; ++ri) {
                                const int m = mw + mt * 16 + l4 * 4 + ri;  // 0..127
                                *(_Float16*)(rp + m * 256 + ((2 * n) ^ SWZ(m))) =
                                    (_Float16)(acc[mt][nt][ri] + bb[ri]);
                            }
                        }
                    }
                }
                __syncthreads();
                #pragma unroll
                for (int i = 0; i < 8; ++i) {
                    const int chunk = i * 4096 + tid * 16;
                    const int m  = chunk >> 8;          // 0..127
                    const int nc = chunk & 255;
                    half8 v = *(const half8*)(rp + m * 256 + (nc ^ SWZ(m)));
                    *(half8*)((char*)vdst + (size_t)(128 * r + m) * (size_t)(LL * 2) + nc) = v;
                }
                __syncthreads();
            }
        }
    }
    #undef X_ISSUE
    #undef X_COMMIT
}

// ================ Kernel B: attention + output projection ==================
#define BH_OFF 0
#define BP_OFF 32768
#define LDS_B  40960

__global__ __launch_bounds__(256, 3)
void attn_out(const float* __restrict__ mask, const _Float16* __restrict__ ws,
              const float* __restrict__ bo, float* __restrict__ out) {
    extern __shared__ char lds[];
    const int tid = threadIdx.x;
    const int wid = tid >> 6;
    const int l15 = tid & 15;
    const int l4  = (tid & 63) >> 4;
    const int b   = blockIdx.x >> 8;
    const int n   = blockIdx.x & 255;

    const _Float16* qt = ws + QBASE + ((size_t)b * LL + n * 64) * CRED;
    const _Float16* kt = qt + MAT_E;
    const _Float16* vt = ws + QBASE + 2 * (size_t)MAT_E + (size_t)b * CRED * LL + n * 64;
    const _Float16* Wo = ws + 3 * (size_t)WELEM;

    // -------- S = (Q^T K)*scale + in-register masked softmax -> P ---------
    {
        const int i0 = wid * 16;
        f32x4 sa[4];
        #pragma unroll
        for (int jt = 0; jt < 4; ++jt) sa[jt] = (f32x4){0.f, 0.f, 0.f, 0.f};
        #pragma unroll
        for (int ks = 0; ks < 8; ++ks) {
            half8 qa = *(const half8*)(qt + (size_t)(i0 + l15) * CRED + ks * 32 + l4 * 8);
            #pragma unroll
            for (int jt = 0; jt < 4; ++jt) {
                half8 kf = *(const half8*)(kt + (size_t)(jt * 16 + l15) * CRED + ks * 32 + l4 * 8);
                sa[jt] = __builtin_amdgcn_mfma_f32_16x16x32_f16(qa, kf, sa[jt], 0, 0, 0);
            }
        }
        float msk[4];
        #pragma unroll
        for (int jt = 0; jt < 4; ++jt)
            msk[jt] = mask[(size_t)b * LL + n * 64 + jt * 16 + l15];
        #pragma unroll
        for (int ri = 0; ri < 4; ++ri) {
            float v[4];
            #pragma unroll
            for (int jt = 0; jt < 4; ++jt)
                v[jt] = (msk[jt] == 0.f) ? -1e30f : sa[jt][ri] * 0.0625f;
            float mx = fmaxf(fmaxf(v[0], v[1]), fmaxf(v[2], v[3]));
            mx = fmaxf(mx, __shfl_xor(mx, 1));
            mx = fmaxf(mx, __shfl_xor(mx, 2));
            mx = fmaxf(mx, __shfl_xor(mx, 4));
            mx = fmaxf(mx, __shfl_xor(mx, 8));
            float e[4], sum = 0.f;
            #pragma unroll
            for (int jt = 0; jt < 4; ++jt) { e[jt] = __expf(v[jt] - mx); sum += e[jt]; }
            sum += __shfl_xor(sum, 1);
            sum += __shfl_xor(sum, 2);
            sum += __shfl_xor(sum, 4);
            sum += __shfl_xor(sum, 8);
            const float inv = 1.f / sum;
            const int i = i0 + l4 * 4 + ri;
            #pragma unroll
            for (int jt = 0; jt < 4; ++jt) {
                const int j = jt * 16 + l15;
                *(_Float16*)(lds + BP_OFF + i * 128 + ((2 * j) ^ SWZ(i))) =
                    (_Float16)(e[jt] * inv);
            }
        }
    }
    __syncthreads();   // P ready

    // -------- H = relu(V @ P^T)  (V frags direct from global) -------------
    {
        const int cb = wid * 64;
        f32x4 pv[4][4];
        #pragma unroll
        for (int m = 0; m < 4; ++m)
            #pragma unroll
            for (int q = 0; q < 4; ++q) pv[m][q] = (f32x4){0.f, 0.f, 0.f, 0.f};
        #pragma unroll
        for (int ks = 0; ks < 2; ++ks) {
            const int kb = ks * 64 + l4 * 16;
            half8 pb[4];
            #pragma unroll
            for (int nt = 0; nt < 4; ++nt) {
                const int i = nt * 16 + l15;
                pb[nt] = *(const half8*)(lds + BP_OFF + i * 128 + (kb ^ SWZ(i)));
            }
            #pragma unroll
            for (int mt = 0; mt < 4; ++mt) {
                half8 va = *(const half8*)(vt + (size_t)(cb + mt * 16 + l15) * LL + ks * 32 + l4 * 8);
                #pragma unroll
                for (int nt = 0; nt < 4; ++nt)
                    pv[mt][nt] = __builtin_amdgcn_mfma_f32_16x16x32_f16(va, pb[nt], pv[mt][nt], 0, 0, 0);
            }
        }
        #pragma unroll
        for (int mt = 0; mt < 4; ++mt) {
            const int c0 = cb + mt * 16 + l4 * 4;
            #pragma unroll
            for (int nt = 0; nt < 4; ++nt) {
                const int j = nt * 16 + l15;
                union { _Float16 h[4]; uint64_t q; } hp;
                #pragma unroll
                for (int ri = 0; ri < 4; ++ri)
                    hp.h[ri] = (_Float16)fmaxf(pv[mt][nt][ri], 0.f);
                *(uint64_t*)(lds + BH_OFF + j * 512 + ((2 * c0) ^ SWZ(j))) = hp.q;
            }
        }
    }
    __syncthreads();   // H ready

    // -------- Out = Wo @ H + bo  (M=512, K=256, N=64) ---------------------
    #pragma unroll
    for (int op = 0; op < 2; ++op) {
        const int mbo = wid * 128 + op * 64;
        const _Float16* wob = Wo + (size_t)(mbo + l15) * CRED + l4 * 8;
        f32x4 oa[4][4];
        #pragma unroll
        for (int m = 0; m < 4; ++m)
            #pragma unroll
            for (int q = 0; q < 4; ++q) oa[m][q] = (f32x4){0.f, 0.f, 0.f, 0.f};
        #pragma unroll 4
        for (int ks = 0; ks < 8; ++ks) {
            const int kb = ks * 64 + l4 * 16;
            half8 hb[4];
            #pragma unroll
            for (int nt = 0; nt < 4; ++nt) {
                const int i = nt * 16 + l15;
                hb[nt] = *(const half8*)(lds + BH_OFF + i * 512 + (kb ^ SWZ(i)));
            }
            #pragma unroll
            for (int mt = 0; mt < 4; ++mt) {
                half8 wa = *(const half8*)(wob + mt * 16 * CRED + ks * 32);
                #pragma unroll
                for (int nt = 0; nt < 4; ++nt)
                    oa[mt][nt] = __builtin_amdgcn_mfma_f32_16x16x32_f16(wa, hb[nt], oa[mt][nt], 0, 0, 0);
            }
        }
        #pragma unroll
        for (int mt = 0; mt < 4; ++mt) {
            const int o0 = mbo + mt * 16 + l4 * 4;
            f32x4 bov = *(const f32x4*)(bo + o0);
            #pragma unroll
            for (int ri = 0; ri < 4; ++ri) {
                float* orow = out + ((size_t)b * CIN + (o0 + ri)) * LL + n * 64;
                #pragma unroll
                for (int nt = 0; nt < 4; ++nt)
                    orow[nt * 16 + l15] = oa[mt][nt][ri] + bov[ri];
            }
        }
    }
}

// ================= Fallback: R5 fused kernel (verified, 168 us) ============
#define XT_OFF 0
#define Q_OFF  0
#define K_OFF  32768
#define V_OFF  32768
#define H_OFF  0
#define P_OFF  65536
#define MSK_OFF 73728
#define LDS_BYTES 73984

__global__ __launch_bounds__(256, 2)
void att_fused(const float* __restrict__ x1, const float* __restrict__ mask,
               const _Float16* __restrict__ W,
               const float* __restrict__ bq, const float* __restrict__ bk,
               const float* __restrict__ bv, const float* __restrict__ bo,
               float* __restrict__ out) {
    extern __shared__ char lds[];
    const int tid  = threadIdx.x;
    const int wid  = tid >> 6;
    const int lane = tid & 63;
    const int l15  = lane & 15;
    const int l4   = lane >> 4;
    const int blk  = blockIdx.x;
    const int b    = blk >> 8;
    const int n    = blk & 255;

    const _Float16* Wq = W;
    const _Float16* Wk = W + WELEM;
    const _Float16* Wv = W + 2 * WELEM;
    const _Float16* Wo = W + 3 * WELEM;

    {
        const int jx = tid & 15;
        const int rb = tid >> 4;
        const float* xbase = x1 + ((size_t)b * CIN + 2 * rb) * LL + n * 64 + 4 * jx;
        #pragma unroll
        for (int i = 0; i < 16; ++i) {
            f32x4 a = *(const f32x4*)(xbase + (size_t)(32 * i) * LL);
            f32x4 c = *(const f32x4*)(xbase + (size_t)(32 * i + 1) * LL);
            const int col = 4 * rb + 64 * i;
            #pragma unroll
            for (int u = 0; u < 4; ++u) {
                union { _Float16 h[2]; uint32_t w; } p;
                p.h[0] = (_Float16)a[u];
                p.h[1] = (_Float16)c[u];
                const int j = 4 * jx + u;
                *(uint32_t*)(lds + XT_OFF + j * 1024 + (col ^ SWZ(j))) = p.w;
            }
        }
        if (tid < 64)
            *(float*)(lds + MSK_OFF + tid * 4) = mask[(size_t)b * LL + n * 64 + tid];
    }
    __syncthreads();

    uint64_t qh[4][4], kh[4][4], vh[4][4];
    #pragma unroll
    for (int pass = 0; pass < 4; ++pass) {
        f32x4 aQ[4], aK[4], aV[4];
        #pragma unroll
        for (int q = 0; q < 4; ++q) {
            aQ[q] = (f32x4){0.f, 0.f, 0.f, 0.f};
            aK[q] = (f32x4){0.f, 0.f, 0.f, 0.f};
            aV[q] = (f32x4){0.f, 0.f, 0.f, 0.f};
        }
        const int mrow = wid * 64 + pass * 16 + l15;
        const _Float16* wqp = Wq + (size_t)mrow * CIN + l4 * 8;
        const _Float16* wkp = Wk + (size_t)mrow * CIN + l4 * 8;
        const _Float16* wvp = Wv + (size_t)mrow * CIN + l4 * 8;
        #pragma unroll 4
        for (int ks = 0; ks < 16; ++ks) {
            const int kb = ks * 64 + l4 * 16;
            half8 xb[4];
            #pragma unroll
            for (int nt = 0; nt < 4; ++nt) {
                const int j = nt * 16 + l15;
                xb[nt] = *(const half8*)(lds + XT_OFF + j * 1024 + (kb ^ SWZ(j)));
            }
            half8 aq = *(const half8*)(wqp + ks * 32);
            half8 ak = *(const half8*)(wkp + ks * 32);
            half8 av = *(const half8*)(wvp + ks * 32);
            #pragma unroll
            for (int nt = 0; nt < 4; ++nt) {
                aQ[nt] = __builtin_amdgcn_mfma_f32_16x16x32_f16(aq, xb[nt], aQ[nt], 0, 0, 0);
                aK[nt] = __builtin_amdgcn_mfma_f32_16x16x32_f16(ak, xb[nt], aK[nt], 0, 0, 0);
                aV[nt] = __builtin_amdgcn_mfma_f32_16x16x32_f16(av, xb[nt], aV[nt], 0, 0, 0);
            }
        }
        const int c0 = wid * 64 + pass * 16 + l4 * 4;
        f32x4 bqv = *(const f32x4*)(bq + c0);
        f32x4 bkv = *(const f32x4*)(bk + c0);
        f32x4 bvv = *(const f32x4*)(bv + c0);
        #pragma unroll
        for (int nt = 0; nt < 4; ++nt) {
            union { _Float16 h[4]; uint64_t q; } qp, kp, vp;
            #pragma unroll
            for (int ri = 0; ri < 4; ++ri) {
                qp.h[ri] = (_Float16)(aQ[nt][ri] + bqv[ri]);
                kp.h[ri] = (_Float16)(aK[nt][ri] + bkv[ri]);
                vp.h[ri] = (_Float16)(aV[nt][ri] + bvv[ri]);
            }
            qh[pass][nt] = qp.q;
            kh[pass][nt] = kp.q;
            vh[pass][nt] = vp.q;
        }
    }
    __syncthreads();

    #pragma unroll
    for (int pass = 0; pass < 4; ++pass) {
        const int c0 = wid * 64 + pass * 16 + l4 * 4;
        #pragma unroll
        for (int nt = 0; nt < 4; ++nt) {
            const int j = nt * 16 + l15;
            *(uint64_t*)(lds + Q_OFF + j * 512 + ((2 * c0) ^ SWZ(j))) = qh[pass][nt];
            *(uint64_t*)(lds + K_OFF + j * 512 + ((2 * c0) ^ SWZ(j))) = kh[pass][nt];
        }
    }
    __syncthreads();

    {
        const int i0 = wid * 16;
        f32x4 sa[4];
        #pragma unroll
        for (int jt = 0; jt < 4; ++jt) sa[jt] = (f32x4){0.f, 0.f, 0.f, 0.f};
        #pragma unroll
        for (int ks = 0; ks < 8; ++ks) {
            const int kb = ks * 64 + l4 * 16;
            const int iq = i0 + l15;
            half8 qa = *(const half8*)(lds + Q_OFF + iq * 512 + (kb ^ SWZ(iq)));
            #pragma unroll
            for (int jt = 0; jt < 4; ++jt) {
                const int jr = jt * 16 + l15;
                half8 kf = *(const half8*)(lds + K_OFF + jr * 512 + (kb ^ SWZ(jr)));
                sa[jt] = __builtin_amdgcn_mfma_f32_16x16x32_f16(qa, kf, sa[jt], 0, 0, 0);
            }
        }
        float msk[4];
        #pragma unroll
        for (int jt = 0; jt < 4; ++jt)
            msk[jt] = *(const float*)(lds + MSK_OFF + (jt * 16 + l15) * 4);
        #pragma unroll
        for (int ri = 0; ri < 4; ++ri) {
            float v[4];
            #pragma unroll
            for (int jt = 0; jt < 4; ++jt)
                v[jt] = (msk[jt] == 0.f) ? -1e30f : sa[jt][ri] * 0.0625f;
            float mx = fmaxf(fmaxf(v[0], v[1]), fmaxf(v[2], v[3]));
            mx = fmaxf(mx, __shfl_xor(mx, 1));
            mx = fmaxf(mx, __shfl_xor(mx, 2));
            mx = fmaxf(mx, __shfl_xor(mx, 4));
            mx = fmaxf(mx, __shfl_xor(mx, 8));
            float e[4], sum = 0.f;
            #pragma unroll
            for (int jt = 0; jt < 4; ++jt) { e[jt] = __expf(v[jt] - mx); sum += e[jt]; }
            sum += __shfl_xor(sum, 1);
            sum += __shfl_xor(sum, 2);
            sum += __shfl_xor(sum, 4);
            sum += __shfl_xor(sum, 8);
            const float inv = 1.f / sum;
            const int i = i0 + l4 * 4 + ri;
            #pragma unroll
            for (int jt = 0; jt < 4; ++jt) {
                const int j = jt * 16 + l15;
                *(_Float16*)(lds + P_OFF + i * 128 + ((2 * j) ^ SWZ(i))) =
                    (_Float16)(e[jt] * inv);
            }
        }
    }
    __syncthreads();

    #pragma unroll
    for (int pass = 0; pass < 4; ++pass) {
        const int c0 = wid * 64 + pass * 16 + l4 * 4;
        #pragma unroll
        for (int nt = 0; nt < 4; ++nt) {
            const int j = nt * 16 + l15;
            const uint64_t v64 = vh[pass][nt];
            #pragma unroll
            for (int ri = 0; ri < 4; ++ri) {
                const int c = c0 + ri;
                *(uint16_t*)(lds + V_OFF + c * 128 + ((2 * j) ^ SWZ(c))) =
                    (uint16_t)(v64 >> (16 * ri));
            }
        }
    }
    __syncthreads();

    {
        const int cb = wid * 64;
        f32x4 pv[4][4];
        #pragma unroll
        for (int m = 0; m < 4; ++m)
            #pragma unroll
            for (int q = 0; q < 4; ++q) pv[m][q] = (f32x4){0.f, 0.f, 0.f, 0.f};
        #pragma unroll
        for (int ks = 0; ks < 2; ++ks) {
            const int kb = ks * 64 + l4 * 16;
            half8 pb[4];
            #pragma unroll
            for (int nt = 0; nt < 4; ++nt) {
                const int i = nt * 16 + l15;
                pb[nt] = *(const half8*)(lds + P_OFF + i * 128 + (kb ^ SWZ(i)));
            }
            #pragma unroll
            for (int mt = 0; mt < 4; ++mt) {
                const int c = cb + mt * 16 + l15;
                half8 va = *(const half8*)(lds + V_OFF + c * 128 + (kb ^ SWZ(c)));
                #pragma unroll
                for (int nt = 0; nt < 4; ++nt)
                    pv[mt][nt] = __builtin_amdgcn_mfma_f32_16x16x32_f16(va, pb[nt], pv[mt][nt], 0, 0, 0);
            }
        }
        #pragma unroll
        for (int mt = 0; mt < 4; ++mt) {
            const int c0 = cb + mt * 16 + l4 * 4;
            #pragma unroll
            for (int nt = 0; nt < 4; ++nt) {
                const int j = nt * 16 + l15;
                union { _Float16 h[4]; uint64_t q; } hp;
                #pragma unroll
                for (int ri = 0; ri < 4; ++ri)
                    hp.h[ri] = (_Float16)fmaxf(pv[mt][nt][ri], 0.f);
                *(uint64_t*)(lds + H_OFF + j * 512 + ((2 * c0) ^ SWZ(j))) = hp.q;
            }
        }
    }
    __syncthreads();

    #pragma unroll
    for (int op = 0; op < 2; ++op) {
        const int mbo = wid * 128 + op * 64;
        const _Float16* wob = Wo + (size_t)(mbo + l15) * CRED + l4 * 8;
        f32x4 oa[4][4];
        #pragma unroll
        for (int m = 0; m < 4; ++m)
            #pragma unroll
            for (int q = 0; q < 4; ++q) oa[m][q] = (f32x4){0.f, 0.f, 0.f, 0.f};
        #pragma unroll 4
        for (int ks = 0; ks < 8; ++ks) {
            const int kb = ks * 64 + l4 * 16;
            half8 hb[4];
            #pragma unroll
            for (int nt = 0; nt < 4; ++nt) {
                const int i = nt * 16 + l15;
                hb[nt] = *(const half8*)(lds + H_OFF + i * 512 + (kb ^ SWZ(i)));
            }
            #pragma unroll
            for (int mt = 0; mt < 4; ++mt) {
                half8 wa = *(const half8*)(wob + mt * 16 * CRED + ks * 32);
                #pragma unroll
                for (int nt = 0; nt < 4; ++nt)
                    oa[mt][nt] = __builtin_amdgcn_mfma_f32_16x16x32_f16(wa, hb[nt], oa[mt][nt], 0, 0, 0);
            }
        }
        #pragma unroll
        for (int mt = 0; mt < 4; ++mt) {
            const int o0 = mbo + mt * 16 + l4 * 4;
            f32x4 bov = *(const f32x4*)(bo + o0);
            #pragma unroll
            for (int ri = 0; ri < 4; ++ri) {
                float* orow = out + ((size_t)b * CIN + (o0 + ri)) * LL + n * 64;
                #pragma unroll
                for (int nt = 0; nt < 4; ++nt)
                    orow[nt * 16 + l15] = oa[mt][nt][ri] + bov[ri];
            }
        }
    }
}

extern "C" void kernel_launch(void* const* d_in, const int* in_sizes, int n_in,
                              void* d_out, int out_size, void* d_ws, size_t ws_size,
                              hipStream_t stream) {
    const float* x1   = (const float*)d_in[0];
    // d_in[1] = x2 : unused by the reference
    const float* mask = (const float*)d_in[2];
    const float* Wq   = (const float*)d_in[3];
    const float* bq   = (const float*)d_in[4];
    const float* Wk   = (const float*)d_in[5];
    const float* bk   = (const float*)d_in[6];
    const float* Wv   = (const float*)d_in[7];
    const float* bv   = (const float*)d_in[8];
    const float* Wo   = (const float*)d_in[9];
    const float* bo   = (const float*)d_in[10];
    float* out = (float*)d_out;
    _Float16* wbuf = (_Float16*)d_ws;

    convert_weights<<<2048, 256, 0, stream>>>(Wq, Wk, Wv, Wo, wbuf);

    if (ws_size >= WS_NEED) {
        (void)hipFuncSetAttribute((const void*)qkv_gemm,
                                  hipFuncAttributeMaxDynamicSharedMemorySize, 65536);
        qkv_gemm<<<BB * 128, 256, 65536, stream>>>(x1, wbuf, bq, bk, bv, wbuf);
        attn_out<<<BB * NBLK, 256, LDS_B, stream>>>(mask, wbuf, bo, out);
    } else {
        (void)hipFuncSetAttribute((const void*)att_fused,
                                  hipFuncAttributeMaxDynamicSharedMemorySize, LDS_BYTES);
        att_fused<<<BB * NBLK, 256, LDS_BYTES, stream>>>(x1, mask, wbuf, bq, bk, bv, bo, out);
    }
}